// Round 6
// baseline (221.215 us; speedup 1.0000x reference)
//
#include <hip/hip_runtime.h>
#include <stdint.h>
#include <math.h>

#define BB 64
#define SS 2048
#define DD 128
#define NB 48
#define NTOK 100000
#define HALF 8388608u   // (BB*SS*DD)/2 = 2^23
#define KL_OFF (BB*NB*DD) // 393216
#define WIN 8

__device__ __forceinline__ uint32_t rotl32(uint32_t x, uint32_t r){ return (x<<r)|(x>>(32u-r)); }

// JAX threefry2x32 with key = (0, 42) — bit-exact, do not touch.
__device__ __forceinline__ uint2 threefry_0_42(uint32_t x0, uint32_t x1){
  const uint32_t ks0 = 0u, ks1 = 42u, ks2 = 0x1BD11BDAu ^ 0u ^ 42u; // 0x1BD11BF0
  x0 += ks0; x1 += ks1;
#define TF_ROUND(r) { x0 += x1; x1 = rotl32(x1, r); x1 ^= x0; }
  TF_ROUND(13u) TF_ROUND(15u) TF_ROUND(26u) TF_ROUND(6u)
  x0 += ks1; x1 += ks2 + 1u;
  TF_ROUND(17u) TF_ROUND(29u) TF_ROUND(16u) TF_ROUND(24u)
  x0 += ks2; x1 += ks0 + 2u;
  TF_ROUND(13u) TF_ROUND(15u) TF_ROUND(26u) TF_ROUND(6u)
  x0 += ks0; x1 += ks1 + 3u;
  TF_ROUND(17u) TF_ROUND(29u) TF_ROUND(16u) TF_ROUND(24u)
  x0 += ks1; x1 += ks2 + 4u;
  TF_ROUND(13u) TF_ROUND(15u) TF_ROUND(26u) TF_ROUND(6u)
  x0 += ks2; x1 += ks0 + 5u;
#undef TF_ROUND
  return make_uint2(x0, x1);
}

// Branchless fast erfinv (Giles coeffs, HW log/sqrt). Tolerance-checked path only.
__device__ __forceinline__ float fast_erfinv(float x){
  float w = -__logf(__fmaf_rn(x, -x, 1.0f));
  bool c = w < 5.0f;
  float t = c ? (w - 2.5f) : (__builtin_amdgcn_sqrtf(w) - 3.0f);
  float p =              c ? 2.81022636e-08f : -0.000200214257f;
  p = __fmaf_rn(p, t,    c ? 3.43273939e-07f : 0.000100950558f);
  p = __fmaf_rn(p, t,    c ? -3.5233877e-06f : 0.00134934322f);
  p = __fmaf_rn(p, t,    c ? -4.39150654e-06f : -0.00367342844f);
  p = __fmaf_rn(p, t,    c ? 0.00021858087f  : 0.00573950773f);
  p = __fmaf_rn(p, t,    c ? -0.00125372503f : -0.0076224613f);
  p = __fmaf_rn(p, t,    c ? -0.00417768164f : 0.00943887047f);
  p = __fmaf_rn(p, t,    c ? 0.246640727f    : 1.00167406f);
  p = __fmaf_rn(p, t,    c ? 1.50140941f     : 2.83297682f);
  return p * x;
}

__device__ __forceinline__ float jax_normal_from_bits(uint32_t bits){
  float f   = __uint_as_float((bits >> 9) | 0x3F800000u);
  float u01 = f - 1.0f;                          // [0,1), exact
  const float lo = __uint_as_float(0xBF7FFFFFu); // nextafter(-1,0)
  float u = fmaxf(lo, __fmaf_rn(u01, 2.0f, lo));
  return 1.41421356237f * fast_erfinv(u);
}

// K0: unchanged (passed). lsum association BIT-EXACT — do not touch.
__global__ __launch_bounds__(256) void k_prep(const float4* __restrict__ W4,
                                              float* __restrict__ lsum,
                                              float* __restrict__ g){
  __shared__ float mu_s[8][128];
  __shared__ float lv_s[8][128];
  __shared__ float gpart[8][32];
  __shared__ float apart[8][8];
  int t = threadIdx.x;
  int blk = blockIdx.x;
  #pragma unroll
  for (int h=0; h<2; h++){
    int q = h*256 + t;          // 0..511 = 8 tokens x 64 float4
    int r = q >> 6, c = q & 63;
    float4 v = W4[(size_t)blk*512 + q];
    if (c < 32) ((float4*)mu_s[r])[c]      = v;
    else        ((float4*)lv_s[r])[c - 32] = v;
  }
  __syncthreads();
  {
    int tl = t>>5, i = t&31;
    float gp = 0.f;
    #pragma unroll
    for (int c=0;c<4;c++){
      int d = i + 32*c;
      float mu = mu_s[tl][d], lv = lv_s[tl][d];
      gp += (-1.0f - lv) + mu*mu + __expf(lv);
    }
    gpart[tl][i] = gp;
  }
  if (t < 64){
    int tl = t>>3, j = t&7;
    float a = lv_s[tl][j];
    #pragma unroll
    for (int k=1;k<16;k++) a = __fadd_rn(a, lv_s[tl][8*k+j]);
    apart[tl][j] = a;
  }
  __syncthreads();
  if (t < 8){
    const float* p = apart[t];
    float s01 = __fadd_rn(p[0],p[1]);
    float s23 = __fadd_rn(p[2],p[3]);
    float s45 = __fadd_rn(p[4],p[5]);
    float s67 = __fadd_rn(p[6],p[7]);
    lsum[blk*8 + t] = __fadd_rn(__fadd_rn(s01,s23), __fadd_rn(s45,s67));
    float gs = 0.f;
    #pragma unroll
    for (int i=0;i<32;i++) gs += gpart[t][i];
    g[blk*8 + t] = gs;
  }
}

// K1a: fully-parallel gather + h compute + kl. h arithmetic IDENTICAL ops to the
// verified k_bins front-end (values bit-exact; stored/reloaded as exact f32).
__global__ __launch_bounds__(256) void k_h(const float* __restrict__ X,
                                           const float* __restrict__ lsum,
                                           const float* __restrict__ g,
                                           float* __restrict__ hbuf,
                                           float* __restrict__ out){
  __shared__ float redk[4];
  int t = threadIdx.x;
  float twopi_f = (float)(2.0 * M_PI);
  float L = (float)log((double)twopi_f);
  float C1 = __fadd_rn(128.0f, __fmul_rn(128.0f, L));
  float klacc = 0.f;
  #pragma unroll
  for (int k=0; k<2; k++){
    int i = blockIdx.x*512 + k*256 + t;   // [0, 131072)
    float T   = X[i*2 + 0];
    int  tok  = (int)X[i*2 + 1];
    float ls  = lsum[tok];
    klacc    += g[tok];
    float h   = __fmul_rn(0.5f, __fadd_rn(C1, ls));
    float mask = (T < 48.0f) ? 1.0f : 0.0f;
    hbuf[i] = __fmul_rn(h, mask);
  }
  #pragma unroll
  for (int o=32; o>0; o>>=1) klacc += __shfl_down(klacc, o);
  if ((t & 63) == 0) redk[t >> 6] = klacc;
  __syncthreads();
  if (t == 0)
    atomicAdd(&out[KL_OFF], (redk[0]+redk[1]+redk[2]+redk[3]) * (0.5f/64.0f));
}

// K1b: Brent-Kung scan — recursion arithmetic BYTE-IDENTICAL to verified version.
__global__ __launch_bounds__(1024) void k_scan(const float* __restrict__ hbuf,
                                               int8_t* __restrict__ bins){
  __shared__ float buf[4096];   // level L at offset 4096 - (4096>>L), size 2048>>L
  __shared__ float redm[16];
  int b = blockIdx.x, t = threadIdx.x;
  for (int s=t; s<SS; s+=1024) buf[s] = hbuf[b*SS + s];
  __syncthreads();
  {
    int offL = 0, sz = SS;
    for (int lev=0; lev<11; lev++){
      int n = sz >> 1; int offN = offL + sz;
      for (int k=t; k<n; k+=1024)
        buf[offN + k] = __fadd_rn(buf[offL + 2*k], buf[offL + 2*k + 1]);
      __syncthreads();
      offL = offN; sz = n;
    }
  }
  for (int lev=10; lev>=0; lev--){
    int offC = 4096 - (4096 >> lev);
    int offN = 4096 - (4096 >> (lev+1));
    int half = (2048 >> lev) >> 1;
    for (int k=t; k<half; k+=1024){
      float odd  = buf[offN + k];
      float even = (k == 0) ? buf[offC] : __fadd_rn(buf[offN + k - 1], buf[offC + 2*k]);
      buf[offC + 2*k]     = even;
      buf[offC + 2*k + 1] = odd;
    }
    __syncthreads();
  }
  float m = fmaxf(buf[t], buf[t + 1024]);
  #pragma unroll
  for (int o=32; o>0; o>>=1) m = fmaxf(m, __shfl_down(m, o));
  if ((t & 63) == 0) redm[t >> 6] = m;
  __syncthreads();
  float maxv = redm[0];
  #pragma unroll
  for (int i=1;i<16;i++) maxv = fmaxf(maxv, redm[i]);
  for (int s=t; s<SS; s+=1024){
    float norm = __fdiv_rn(buf[s], maxv);
    int bin = (int)floorf(__fmul_rn(norm, 48.0f));
    bool valid = (norm >= 0.0f) && (norm < 1.0f);
    bins[b*SS + s] = valid ? (int8_t)bin : (int8_t)(-1);
  }
}

// K2: LDS-staged toks/bins; depth-2 software pipeline, manual unroll x2 (NO
// pragma unroll — spill tripwire is WRITE_SIZE); register-run accumulation.
#define K2_BODY(SLOT, MU0, LV0, MU1, LV1)                                     \
  {                                                                           \
    int sl = (SLOT);                                                          \
    int s = chunk*32 + sl;                                                    \
    uint32_t i32 = (uint32_t)(bp*SS + s) * 128u + (uint32_t)lane;             \
    uint2 rr = threefry_0_42(i32, i32 + HALF);                                \
    float e0 = __fmaf_rn(__expf(0.5f*(LV0)), jax_normal_from_bits(rr.x), (MU0)); \
    float e1 = __fmaf_rn(__expf(0.5f*(LV1)), jax_normal_from_bits(rr.y), (MU1)); \
    int b0 = bin_s[0][sl];                                                    \
    int b1 = bin_s[1][sl];                                                    \
    if (b0 != cur0){                                                          \
      if (cur0 >= 0){                                                         \
        int o = cur0 - base0;                                                 \
        if (o < WIN) atomicAdd(&acc[o*DD + lane], r0);                        \
        else atomicAdd(&out[(bp*NB + cur0)*DD + lane], r0);                   \
      }                                                                       \
      cur0 = b0; r0 = 0.f;                                                    \
    }                                                                         \
    if (b0 >= 0) r0 += e0;                                                    \
    if (b1 != cur1){                                                          \
      if (cur1 >= 0){                                                         \
        int o = cur1 - base1;                                                 \
        if (o < WIN) atomicAdd(&acc[WIN*DD + o*DD + lane], r1);               \
        else atomicAdd(&out[((bp+32)*NB + cur1)*DD + lane], r1);              \
      }                                                                       \
      cur1 = b1; r1 = 0.f;                                                    \
    }                                                                         \
    if (b1 >= 0) r1 += e1;                                                    \
  }

__global__ __launch_bounds__(256, 8) void k_accum(const float* __restrict__ X, const float* __restrict__ W,
                                                  const int8_t* __restrict__ bins,
                                                  float* __restrict__ out){
  __shared__ float acc[2*WIN*DD];   // 8 KB
  __shared__ int   tok_s[2][32];
  __shared__ int   bin_s[2][32];
  __shared__ int   hi_s[2];
  int t = threadIdx.x;
  int bp = blockIdx.x >> 6;          // rows (bp, bp+32)
  int chunk = blockIdx.x & 63;       // 32 positions
  int sub = t >> 7, lane = t & 127;
  for (int i=t; i<2*WIN*DD; i+=256) acc[i] = 0.f;
  if (t < 128){
    int r = (t >> 5) & 1, i = t & 31;
    int row = bp + r*32;
    if (t < 64) tok_s[r][i] = (int)X[(row*SS + chunk*32 + i)*2 + 1];
    else        bin_s[r][i] = (int)bins[row*SS + chunk*32 + i];
  }
  __syncthreads();
  if (t < 2){
    int h = -1;
    for (int i=0;i<32;i++) h = max(h, bin_s[t][i]);
    hi_s[t] = h;
  }
  int base0 = bin_s[0][0], base1 = bin_s[1][0];
  // prefetch stage A (it=0) and stage B (it=1)
  float mu0A, lv0A, mu1A, lv1A, mu0B, lv0B, mu1B, lv1B;
  {
    int a0 = tok_s[0][sub], a1 = tok_s[1][sub];
    mu0A = W[a0*256 + lane]; lv0A = W[a0*256 + 128 + lane];
    mu1A = W[a1*256 + lane]; lv1A = W[a1*256 + 128 + lane];
  }
  {
    int a0 = tok_s[0][2+sub], a1 = tok_s[1][2+sub];
    mu0B = W[a0*256 + lane]; lv0B = W[a0*256 + 128 + lane];
    mu1B = W[a1*256 + lane]; lv1B = W[a1*256 + 128 + lane];
  }
  int cur0 = -1, cur1 = -1;
  float r0 = 0.f, r1 = 0.f;
  for (int it=0; it<16; it+=2){
    // prefetch it+2, consume stage A (it)
    float n0=0.f, n1=0.f, n2=0.f, n3=0.f;
    if (it+2 < 16){
      int sl = (it+2)*2 + sub;
      int a0 = tok_s[0][sl], a1 = tok_s[1][sl];
      n0 = W[a0*256 + lane]; n1 = W[a0*256 + 128 + lane];
      n2 = W[a1*256 + lane]; n3 = W[a1*256 + 128 + lane];
    }
    K2_BODY(it*2 + sub, mu0A, lv0A, mu1A, lv1A)
    mu0A = n0; lv0A = n1; mu1A = n2; lv1A = n3;
    // prefetch it+3, consume stage B (it+1)
    float m0=0.f, m1=0.f, m2=0.f, m3=0.f;
    if (it+3 < 16){
      int sl = (it+3)*2 + sub;
      int a0 = tok_s[0][sl], a1 = tok_s[1][sl];
      m0 = W[a0*256 + lane]; m1 = W[a0*256 + 128 + lane];
      m2 = W[a1*256 + lane]; m3 = W[a1*256 + 128 + lane];
    }
    K2_BODY((it+1)*2 + sub, mu0B, lv0B, mu1B, lv1B)
    mu0B = m0; lv0B = m1; mu1B = m2; lv1B = m3;
  }
  if (cur0 >= 0){
    int o = cur0 - base0;
    if (o < WIN) atomicAdd(&acc[o*DD + lane], r0);
    else atomicAdd(&out[(bp*NB + cur0)*DD + lane], r0);
  }
  if (cur1 >= 0){
    int o = cur1 - base1;
    if (o < WIN) atomicAdd(&acc[WIN*DD + o*DD + lane], r1);
    else atomicAdd(&out[((bp+32)*NB + cur1)*DD + lane], r1);
  }
  __syncthreads();
  int hi0 = hi_s[0], hi1 = hi_s[1];
  int top0 = min(hi0, base0 + WIN - 1);
  if (base0 >= 0 && top0 >= base0){
    int total = (top0 - base0 + 1)*DD;
    for (int q=t; q<total; q+=256){
      int o = q >> 7, dim = q & 127;
      atomicAdd(&out[(bp*NB + base0 + o)*DD + dim], acc[o*DD + dim]);
    }
  }
  int top1 = min(hi1, base1 + WIN - 1);
  if (base1 >= 0 && top1 >= base1){
    int total = (top1 - base1 + 1)*DD;
    for (int q=t; q<total; q+=256){
      int o = q >> 7, dim = q & 127;
      atomicAdd(&out[((bp+32)*NB + base1 + o)*DD + dim], acc[WIN*DD + o*DD + dim]);
    }
  }
}

extern "C" void kernel_launch(void* const* d_in, const int* in_sizes, int n_in,
                              void* d_out, int out_size, void* d_ws, size_t ws_size,
                              hipStream_t stream){
  const float* X = (const float*)d_in[0];
  const float* W = (const float*)d_in[1];
  float* out  = (float*)d_out;
  float* lsum = (float*)d_ws;                                        // 100000 f
  float* g    = (float*)((char*)d_ws + 400000);                      // 100000 f
  int8_t* bins = (int8_t*)((char*)d_ws + 800000);                    // 131072 B
  float* hbuf = (float*)((char*)d_ws + 931072);                      // 131072 f (16B-aligned)
  (void)in_sizes; (void)n_in; (void)ws_size;
  hipMemsetAsync(d_out, 0, (size_t)out_size*sizeof(float), stream);
  k_prep <<<NTOK/8, 256, 0, stream>>>((const float4*)W, lsum, g);
  k_h    <<<256,    256, 0, stream>>>(X, lsum, g, hbuf, out);
  k_scan <<<BB,    1024, 0, stream>>>(hbuf, bins);
  k_accum<<<2048,   256, 0, stream>>>(X, W, bins, out);
}

// Round 7
// 207.902 us; speedup vs baseline: 1.0640x; 1.0640x over previous
//
#include <hip/hip_runtime.h>
#include <stdint.h>
#include <math.h>

#define BB 64
#define SS 2048
#define DD 128
#define NB 48
#define NTOK 100000
#define HALF 8388608u   // (BB*SS*DD)/2 = 2^23
#define KL_OFF (BB*NB*DD) // 393216
#define WIN 8

__device__ __forceinline__ uint32_t rotl32(uint32_t x, uint32_t r){ return (x<<r)|(x>>(32u-r)); }

// JAX threefry2x32 with key = (0, 42) — bit-exact, do not touch.
__device__ __forceinline__ uint2 threefry_0_42(uint32_t x0, uint32_t x1){
  const uint32_t ks0 = 0u, ks1 = 42u, ks2 = 0x1BD11BDAu ^ 0u ^ 42u; // 0x1BD11BF0
  x0 += ks0; x1 += ks1;
#define TF_ROUND(r) { x0 += x1; x1 = rotl32(x1, r); x1 ^= x0; }
  TF_ROUND(13u) TF_ROUND(15u) TF_ROUND(26u) TF_ROUND(6u)
  x0 += ks1; x1 += ks2 + 1u;
  TF_ROUND(17u) TF_ROUND(29u) TF_ROUND(16u) TF_ROUND(24u)
  x0 += ks2; x1 += ks0 + 2u;
  TF_ROUND(13u) TF_ROUND(15u) TF_ROUND(26u) TF_ROUND(6u)
  x0 += ks0; x1 += ks1 + 3u;
  TF_ROUND(17u) TF_ROUND(29u) TF_ROUND(16u) TF_ROUND(24u)
  x0 += ks1; x1 += ks2 + 4u;
  TF_ROUND(13u) TF_ROUND(15u) TF_ROUND(26u) TF_ROUND(6u)
  x0 += ks2; x1 += ks0 + 5u;
#undef TF_ROUND
  return make_uint2(x0, x1);
}

// Branchless fast erfinv (Giles coeffs, HW log/sqrt). Tolerance-checked path only.
__device__ __forceinline__ float fast_erfinv(float x){
  float w = -__logf(__fmaf_rn(x, -x, 1.0f));
  bool c = w < 5.0f;
  float t = c ? (w - 2.5f) : (__builtin_amdgcn_sqrtf(w) - 3.0f);
  float p =              c ? 2.81022636e-08f : -0.000200214257f;
  p = __fmaf_rn(p, t,    c ? 3.43273939e-07f : 0.000100950558f);
  p = __fmaf_rn(p, t,    c ? -3.5233877e-06f : 0.00134934322f);
  p = __fmaf_rn(p, t,    c ? -4.39150654e-06f : -0.00367342844f);
  p = __fmaf_rn(p, t,    c ? 0.00021858087f  : 0.00573950773f);
  p = __fmaf_rn(p, t,    c ? -0.00125372503f : -0.0076224613f);
  p = __fmaf_rn(p, t,    c ? -0.00417768164f : 0.00943887047f);
  p = __fmaf_rn(p, t,    c ? 0.246640727f    : 1.00167406f);
  p = __fmaf_rn(p, t,    c ? 1.50140941f     : 2.83297682f);
  return p * x;
}

__device__ __forceinline__ float jax_normal_from_bits(uint32_t bits){
  float f   = __uint_as_float((bits >> 9) | 0x3F800000u);
  float u01 = f - 1.0f;                          // [0,1), exact
  const float lo = __uint_as_float(0xBF7FFFFFu); // nextafter(-1,0)
  float u = fmaxf(lo, __fmaf_rn(u01, 2.0f, lo));
  return 1.41421356237f * fast_erfinv(u);
}

// K0: unchanged (passed). lsum association BIT-EXACT — do not touch.
__global__ __launch_bounds__(256) void k_prep(const float4* __restrict__ W4,
                                              float* __restrict__ lsum,
                                              float* __restrict__ g){
  __shared__ float mu_s[8][128];
  __shared__ float lv_s[8][128];
  __shared__ float gpart[8][32];
  __shared__ float apart[8][8];
  int t = threadIdx.x;
  int blk = blockIdx.x;
  #pragma unroll
  for (int h=0; h<2; h++){
    int q = h*256 + t;          // 0..511 = 8 tokens x 64 float4
    int r = q >> 6, c = q & 63;
    float4 v = W4[(size_t)blk*512 + q];
    if (c < 32) ((float4*)mu_s[r])[c]      = v;
    else        ((float4*)lv_s[r])[c - 32] = v;
  }
  __syncthreads();
  {
    int tl = t>>5, i = t&31;
    float gp = 0.f;
    #pragma unroll
    for (int c=0;c<4;c++){
      int d = i + 32*c;
      float mu = mu_s[tl][d], lv = lv_s[tl][d];
      gp += (-1.0f - lv) + mu*mu + __expf(lv);
    }
    gpart[tl][i] = gp;
  }
  if (t < 64){
    int tl = t>>3, j = t&7;
    float a = lv_s[tl][j];
    #pragma unroll
    for (int k=1;k<16;k++) a = __fadd_rn(a, lv_s[tl][8*k+j]);
    apart[tl][j] = a;
  }
  __syncthreads();
  if (t < 8){
    const float* p = apart[t];
    float s01 = __fadd_rn(p[0],p[1]);
    float s23 = __fadd_rn(p[2],p[3]);
    float s45 = __fadd_rn(p[4],p[5]);
    float s67 = __fadd_rn(p[6],p[7]);
    lsum[blk*8 + t] = __fadd_rn(__fadd_rn(s01,s23), __fadd_rn(s45,s67));
    float gs = 0.f;
    #pragma unroll
    for (int i=0;i<32;i++) gs += gpart[t][i];
    g[blk*8 + t] = gs;
  }
}

// K1: Brent-Kung scan — recursion arithmetic BYTE-IDENTICAL to verified version.
__global__ __launch_bounds__(1024) void k_bins(const float* __restrict__ X, const float* __restrict__ lsum,
                                               const float* __restrict__ g,
                                               int8_t* __restrict__ bins, float* __restrict__ out){
  __shared__ float buf[4096];   // level L at offset 4096 - (4096>>L), size 2048>>L
  __shared__ float redm[16];
  __shared__ float redk[16];
  int b = blockIdx.x, t = threadIdx.x;
  float twopi_f = (float)(2.0 * M_PI);
  float L = (float)log((double)twopi_f);
  float C1 = __fadd_rn(128.0f, __fmul_rn(128.0f, L));
  float klacc = 0.f;
  for (int s=t; s<SS; s+=1024){
    float T    = X[(b*SS+s)*2 + 0];
    int   tok  = (int)X[(b*SS+s)*2 + 1];
    float ls   = lsum[tok];
    klacc     += g[tok];
    float h    = __fmul_rn(0.5f, __fadd_rn(C1, ls));
    float mask = (T < 48.0f) ? 1.0f : 0.0f;
    buf[s] = __fmul_rn(h, mask);
  }
  __syncthreads();
  {
    int offL = 0, sz = SS;
    for (int lev=0; lev<11; lev++){
      int n = sz >> 1; int offN = offL + sz;
      for (int k=t; k<n; k+=1024)
        buf[offN + k] = __fadd_rn(buf[offL + 2*k], buf[offL + 2*k + 1]);
      __syncthreads();
      offL = offN; sz = n;
    }
  }
  for (int lev=10; lev>=0; lev--){
    int offC = 4096 - (4096 >> lev);
    int offN = 4096 - (4096 >> (lev+1));
    int half = (2048 >> lev) >> 1;
    for (int k=t; k<half; k+=1024){
      float odd  = buf[offN + k];
      float even = (k == 0) ? buf[offC] : __fadd_rn(buf[offN + k - 1], buf[offC + 2*k]);
      buf[offC + 2*k]     = even;
      buf[offC + 2*k + 1] = odd;
    }
    __syncthreads();
  }
  float m = fmaxf(buf[t], buf[t + 1024]);
  #pragma unroll
  for (int o=32; o>0; o>>=1) m = fmaxf(m, __shfl_down(m, o));
  if ((t & 63) == 0) redm[t >> 6] = m;
  __syncthreads();
  float maxv = redm[0];
  #pragma unroll
  for (int i=1;i<16;i++) maxv = fmaxf(maxv, redm[i]);
  for (int s=t; s<SS; s+=1024){
    float norm = __fdiv_rn(buf[s], maxv);
    int bin = (int)floorf(__fmul_rn(norm, 48.0f));
    bool valid = (norm >= 0.0f) && (norm < 1.0f);
    bins[b*SS + s] = valid ? (int8_t)bin : (int8_t)(-1);
  }
  #pragma unroll
  for (int o=32; o>0; o>>=1) klacc += __shfl_down(klacc, o);
  if ((t & 63) == 0) redk[t >> 6] = klacc;
  __syncthreads();
  if (t == 0){
    float s = 0.f;
    #pragma unroll
    for (int i=0;i<16;i++) s += redk[i];
    atomicAdd(&out[KL_OFF], s * (0.5f/64.0f));
  }
}

// K2: LDS-staged toks/bins; depth-2 software pipeline at __launch_bounds__(256,6)
// — the (256,8) 64-VGPR cap made the allocator spill pipeline state to scratch
// (r4: 206 MB, r6: 97 MB HBM writes). 6 waves/EU -> ~84 VGPR budget.
// Spill tripwire: WRITE_SIZE must stay ~3.6 MB.
#define K2_BODY(SLOT, MU0, LV0, MU1, LV1)                                     \
  {                                                                           \
    int sl = (SLOT);                                                          \
    int s = chunk*32 + sl;                                                    \
    uint32_t i32 = (uint32_t)(bp*SS + s) * 128u + (uint32_t)lane;             \
    uint2 rr = threefry_0_42(i32, i32 + HALF);                                \
    float e0 = __fmaf_rn(__expf(0.5f*(LV0)), jax_normal_from_bits(rr.x), (MU0)); \
    float e1 = __fmaf_rn(__expf(0.5f*(LV1)), jax_normal_from_bits(rr.y), (MU1)); \
    int b0 = bin_s[0][sl];                                                    \
    int b1 = bin_s[1][sl];                                                    \
    if (b0 != cur0){                                                          \
      if (cur0 >= 0){                                                         \
        int o = cur0 - base0;                                                 \
        if (o < WIN) atomicAdd(&acc[o*DD + lane], r0);                        \
        else atomicAdd(&out[(bp*NB + cur0)*DD + lane], r0);                   \
      }                                                                       \
      cur0 = b0; r0 = 0.f;                                                    \
    }                                                                         \
    if (b0 >= 0) r0 += e0;                                                    \
    if (b1 != cur1){                                                          \
      if (cur1 >= 0){                                                         \
        int o = cur1 - base1;                                                 \
        if (o < WIN) atomicAdd(&acc[WIN*DD + o*DD + lane], r1);               \
        else atomicAdd(&out[((bp+32)*NB + cur1)*DD + lane], r1);              \
      }                                                                       \
      cur1 = b1; r1 = 0.f;                                                    \
    }                                                                         \
    if (b1 >= 0) r1 += e1;                                                    \
  }

__global__ __launch_bounds__(256, 6) void k_accum(const float* __restrict__ X, const float* __restrict__ W,
                                                  const int8_t* __restrict__ bins,
                                                  float* __restrict__ out){
  __shared__ float acc[2*WIN*DD];   // 8 KB
  __shared__ int   tok_s[2][32];
  __shared__ int   bin_s[2][32];
  __shared__ int   hi_s[2];
  int t = threadIdx.x;
  int bp = blockIdx.x >> 6;          // rows (bp, bp+32)
  int chunk = blockIdx.x & 63;       // 32 positions
  int sub = t >> 7, lane = t & 127;
  for (int i=t; i<2*WIN*DD; i+=256) acc[i] = 0.f;
  if (t < 128){
    int r = (t >> 5) & 1, i = t & 31;
    int row = bp + r*32;
    if (t < 64) tok_s[r][i] = (int)X[(row*SS + chunk*32 + i)*2 + 1];
    else        bin_s[r][i] = (int)bins[row*SS + chunk*32 + i];
  }
  __syncthreads();
  if (t < 2){
    int h = -1;
    for (int i=0;i<32;i++) h = max(h, bin_s[t][i]);
    hi_s[t] = h;
  }
  int base0 = bin_s[0][0], base1 = bin_s[1][0];
  // prefetch stage A (it=0) and stage B (it=1)
  float mu0A, lv0A, mu1A, lv1A, mu0B, lv0B, mu1B, lv1B;
  {
    int a0 = tok_s[0][sub], a1 = tok_s[1][sub];
    mu0A = W[a0*256 + lane]; lv0A = W[a0*256 + 128 + lane];
    mu1A = W[a1*256 + lane]; lv1A = W[a1*256 + 128 + lane];
  }
  {
    int a0 = tok_s[0][2+sub], a1 = tok_s[1][2+sub];
    mu0B = W[a0*256 + lane]; lv0B = W[a0*256 + 128 + lane];
    mu1B = W[a1*256 + lane]; lv1B = W[a1*256 + 128 + lane];
  }
  int cur0 = -1, cur1 = -1;
  float r0 = 0.f, r1 = 0.f;
  for (int it=0; it<16; it+=2){
    float n0=0.f, n1=0.f, n2=0.f, n3=0.f;
    if (it+2 < 16){
      int sl = (it+2)*2 + sub;
      int a0 = tok_s[0][sl], a1 = tok_s[1][sl];
      n0 = W[a0*256 + lane]; n1 = W[a0*256 + 128 + lane];
      n2 = W[a1*256 + lane]; n3 = W[a1*256 + 128 + lane];
    }
    K2_BODY(it*2 + sub, mu0A, lv0A, mu1A, lv1A)
    mu0A = n0; lv0A = n1; mu1A = n2; lv1A = n3;
    float m0=0.f, m1=0.f, m2=0.f, m3=0.f;
    if (it+3 < 16){
      int sl = (it+3)*2 + sub;
      int a0 = tok_s[0][sl], a1 = tok_s[1][sl];
      m0 = W[a0*256 + lane]; m1 = W[a0*256 + 128 + lane];
      m2 = W[a1*256 + lane]; m3 = W[a1*256 + 128 + lane];
    }
    K2_BODY((it+1)*2 + sub, mu0B, lv0B, mu1B, lv1B)
    mu0B = m0; lv0B = m1; mu1B = m2; lv1B = m3;
  }
  if (cur0 >= 0){
    int o = cur0 - base0;
    if (o < WIN) atomicAdd(&acc[o*DD + lane], r0);
    else atomicAdd(&out[(bp*NB + cur0)*DD + lane], r0);
  }
  if (cur1 >= 0){
    int o = cur1 - base1;
    if (o < WIN) atomicAdd(&acc[WIN*DD + o*DD + lane], r1);
    else atomicAdd(&out[((bp+32)*NB + cur1)*DD + lane], r1);
  }
  __syncthreads();
  int hi0 = hi_s[0], hi1 = hi_s[1];
  int top0 = min(hi0, base0 + WIN - 1);
  if (base0 >= 0 && top0 >= base0){
    int total = (top0 - base0 + 1)*DD;
    for (int q=t; q<total; q+=256){
      int o = q >> 7, dim = q & 127;
      atomicAdd(&out[(bp*NB + base0 + o)*DD + dim], acc[o*DD + dim]);
    }
  }
  int top1 = min(hi1, base1 + WIN - 1);
  if (base1 >= 0 && top1 >= base1){
    int total = (top1 - base1 + 1)*DD;
    for (int q=t; q<total; q+=256){
      int o = q >> 7, dim = q & 127;
      atomicAdd(&out[((bp+32)*NB + base1 + o)*DD + dim], acc[WIN*DD + o*DD + dim]);
    }
  }
}

extern "C" void kernel_launch(void* const* d_in, const int* in_sizes, int n_in,
                              void* d_out, int out_size, void* d_ws, size_t ws_size,
                              hipStream_t stream){
  const float* X = (const float*)d_in[0];
  const float* W = (const float*)d_in[1];
  float* out  = (float*)d_out;
  float* lsum = (float*)d_ws;                                        // 100000 f
  float* g    = (float*)((char*)d_ws + 400000);                      // 100000 f
  int8_t* bins = (int8_t*)((char*)d_ws + 800000);                    // 131072 B
  (void)in_sizes; (void)n_in; (void)ws_size;
  hipMemsetAsync(d_out, 0, (size_t)out_size*sizeof(float), stream);
  k_prep <<<NTOK/8, 256, 0, stream>>>((const float4*)W, lsum, g);
  k_bins <<<BB,    1024, 0, stream>>>(X, lsum, g, bins, out);
  k_accum<<<2048,   256, 0, stream>>>(X, W, bins, out);
}